// Round 2
// baseline (1430.465 us; speedup 1.0000x reference)
//
#include <hip/hip_runtime.h>
#include <hip/hip_bf16.h>
#include <stdint.h>

#define NROWS 65536   // B*S = 16*4096
#define DDIM  256
#define KCAND 4096
#define CAP   48      // per-row candidate list slots
#define SVCAP (1u<<20)
#define MARGIN1 8e-4f // phase-1 collect margin (worst-case bf16 err 2*2.8e-4 + tie grid)
#define MARGIN2 8e-4f // phase-2 prune margin

typedef __bf16 bf16x8 __attribute__((ext_vector_type(8)));
typedef float  f32x4  __attribute__((ext_vector_type(4)));
typedef unsigned int u32;
typedef unsigned long long u64;

__device__ __forceinline__ u32 f2bf_u(float f) {
    u32 u = __float_as_uint(f);
    u += 0x7fffu + ((u >> 16) & 1u);
    return u >> 16;
}
__device__ __forceinline__ u32 pack2(float lo, float hi) { return f2bf_u(lo) | (f2bf_u(hi) << 16); }
__device__ __forceinline__ u32 fkey(float f) {
    u32 u = __float_as_uint(f);
    return (u & 0x80000000u) ? ~u : (u | 0x80000000u);
}
__device__ __forceinline__ float funkey(u32 k) {
    u32 u = (k & 0x80000000u) ? (k ^ 0x80000000u) : ~k;
    return __uint_as_float(u);
}

// np-semantics exact distance: r = fl(fl(A + b_k) - acc_k), sequential ascending-d FMA
__device__ __forceinline__ float exact_r(const float* __restrict__ xr, float A,
                                         const float* __restrict__ er) {
    float b = 0.f, acc = 0.f;
    #pragma unroll 8
    for (int d = 0; d < DDIM; ++d) {
        float e = er[d];
        b   = fmaf(e, e, b);
        acc = fmaf(2.0f * xr[d], e, acc);
    }
    return (A + b) - acc;
}

// ---------------------------------------------------------------- converts
__global__ void convert_e(const float* __restrict__ e, u32* __restrict__ ebf) {
    int i = blockIdx.x * blockDim.x + threadIdx.x;  // 262144 float4 chunks
    float4 v = ((const float4*)e)[i];
    uint2 o; o.x = pack2(v.x, v.y); o.y = pack2(v.z, v.w);
    ((uint2*)ebf)[i] = o;
}

__launch_bounds__(256)
__global__ void computeA(const float* __restrict__ x, float* __restrict__ A) {
    int row = blockIdx.x * 4 + (threadIdx.x >> 6);
    int L = threadIdx.x & 63;
    float4 v = ((const float4*)(x + (size_t)row * DDIM))[L];
    double s = (double)v.x * v.x + (double)v.y * v.y + (double)v.z * v.z + (double)v.w * v.w;
    #pragma unroll
    for (int o = 32; o; o >>= 1) s += __shfl_xor(s, o, 64);
    if (L == 0) A[row] = (float)s;
}

// ---------------------------------------------------------------- phase 1
// 512 thr = 8 waves (2 row x 4 col), wave-tile 64x64. x-tile resident (64KB,
// XOR-swizzled), e streamed in 64 dbuf'd 32KB chunks (BK=64), 1 barrier/chunk.
__launch_bounds__(512, 2)
__global__ void phase1(const float* __restrict__ x, const u32* __restrict__ ebf,
                       u32* __restrict__ cnt, uint2* __restrict__ list) {
    __shared__ u32 lxd[128 * 128];        // 128 rows x 128 dwords (256 bf16), swizzled
    __shared__ u32 led[2][256 * 32];      // 2 x (256 cands x 32 dwords = 64 bf16)
    __shared__ u32 rowMinU[128];

    const int tid = threadIdx.x;
    const int rowBase = blockIdx.x * 128;
    if (tid < 128) rowMinU[tid] = 0xFFFFFFFFu;

    // stage x tile once: fp32 -> bf16, swizzled
    {
        const float4* x4 = (const float4*)(x + (size_t)rowBase * DDIM);
        #pragma unroll
        for (int j = 0; j < 16; ++j) {
            int idx = j * 512 + tid;          // 0..8191 float4 chunks
            int r = idx >> 6, c4 = idx & 63;
            float4 v = x4[idx];
            int dst = r * 128 + ((2 * c4) ^ ((r & 7) << 2));
            lxd[dst]     = pack2(v.x, v.y);
            lxd[dst + 1] = pack2(v.z, v.w);
        }
    }

    const int L = tid & 63, w = tid >> 6;
    const int wr = w >> 2, wc = w & 3;
    const int lq = L >> 4, ln = L & 15;
    const int swz = (ln & 7) << 2;

    uint4 pf[4];
    auto loadStage = [&](int s) {
        int ct = s >> 2, kc = s & 3;
        #pragma unroll
        for (int i = 0; i < 4; ++i) {
            int idx = i * 512 + tid;          // 0..2047 uint4 chunks
            int q = idx >> 3, c16 = idx & 7;
            pf[i] = *(const uint4*)&ebf[(ct * 256 + q) * 128 + kc * 32 + c16 * 4];
        }
    };
    auto storeStage = [&](int s) {
        int buf = s & 1;
        #pragma unroll
        for (int i = 0; i < 4; ++i) {
            int idx = i * 512 + tid;
            int q = idx >> 3, c16 = idx & 7;
            int dst = q * 32 + ((c16 * 4) ^ ((q & 7) << 2));
            *(uint4*)&led[buf][dst] = pf[i];
        }
    };

    loadStage(0); storeStage(0);
    f32x4 acc[4][4];

    for (int s = 0; s < 64; ++s) {
        __syncthreads();                      // the ONLY barrier per chunk
        const int ct = s >> 2, kc = s & 3, buf = s & 1;
        if (s < 63) loadStage(s + 1);
        if (kc == 0) {
            #pragma unroll
            for (int a = 0; a < 4; ++a)
                #pragma unroll
                for (int u = 0; u < 4; ++u)
                    acc[a][u] = (f32x4){0.f, 0.f, 0.f, 0.f};
        }
        #pragma unroll
        for (int ksub = 0; ksub < 2; ++ksub) {
            bf16x8 fa[4], fb[4];
            #pragma unroll
            for (int t = 0; t < 4; ++t) {
                int R = wr * 64 + t * 16 + ln;
                int c = kc * 32 + ksub * 16 + lq * 4;
                fa[t] = *(const bf16x8*)&lxd[R * 128 + (c ^ swz)];
            }
            #pragma unroll
            for (int u = 0; u < 4; ++u) {
                int q = wc * 64 + u * 16 + ln;
                int c = ksub * 16 + lq * 4;
                fb[u] = *(const bf16x8*)&led[buf][q * 32 + (c ^ swz)];
            }
            #pragma unroll
            for (int a = 0; a < 4; ++a)
                #pragma unroll
                for (int u = 0; u < 4; ++u)
                    acc[a][u] = __builtin_amdgcn_mfma_f32_16x16x32_bf16(fa[a], fb[u], acc[a][u], 0, 0, 0);
        }
        if (kc == 3) {
            // epilogue: barrier-free (rowMinU monotone; stale threshold => superset)
            #pragma unroll
            for (int a = 0; a < 4; ++a) {
                #pragma unroll
                for (int r = 0; r < 4; ++r) {
                    float v0 = -2.f * acc[a][0][r], v1 = -2.f * acc[a][1][r];
                    float v2 = -2.f * acc[a][2][r], v3 = -2.f * acc[a][3][r];
                    float m = fminf(fminf(v0, v1), fminf(v2, v3));
                    int lrow = wr * 64 + a * 16 + lq * 4 + r;
                    u32 mk = fkey(m);
                    u32 old = atomicMin(&rowMinU[lrow], mk);
                    float thr = funkey(old < mk ? old : mk) + MARGIN1;
                    int grow = rowBase + lrow;
                    int kb = ct * 256 + wc * 64 + ln;
                    if (v0 <= thr) { u32 id = atomicAdd(&cnt[grow], 1u); if (id < CAP) list[(size_t)grow * CAP + id] = make_uint2(__float_as_uint(v0), kb); }
                    if (v1 <= thr) { u32 id = atomicAdd(&cnt[grow], 1u); if (id < CAP) list[(size_t)grow * CAP + id] = make_uint2(__float_as_uint(v1), kb + 16); }
                    if (v2 <= thr) { u32 id = atomicAdd(&cnt[grow], 1u); if (id < CAP) list[(size_t)grow * CAP + id] = make_uint2(__float_as_uint(v2), kb + 32); }
                    if (v3 <= thr) { u32 id = atomicAdd(&cnt[grow], 1u); if (id < CAP) list[(size_t)grow * CAP + id] = make_uint2(__float_as_uint(v3), kb + 48); }
                }
            }
        }
        if (s < 63) storeStage(s + 1);
    }
}

// ---------------------------------------------------------------- phase 2a
// per row: prune list to survivors within MARGIN2 of collected min, compact-
// append to global survivor list. Overflow rows: full exact scan inline.
__launch_bounds__(256)
__global__ void phase2a(const float* __restrict__ x, const float* __restrict__ emb,
                        const float* __restrict__ A, const u32* __restrict__ cnt,
                        const uint2* __restrict__ list, u64* __restrict__ rmin,
                        u32* __restrict__ svcount, uint2* __restrict__ survivors) {
    int row = blockIdx.x * 4 + (threadIdx.x >> 6);
    int L = threadIdx.x & 63;
    u32 n = cnt[row];
    if (n <= CAP) {
        float vv = INFINITY; u32 kk = 0;
        if (L < (int)n) { uint2 e = list[(size_t)row * CAP + L]; vv = __uint_as_float(e.x); kk = e.y; }
        float mv = vv;
        #pragma unroll
        for (int o = 32; o; o >>= 1) mv = fminf(mv, __shfl_xor(mv, o, 64));
        bool pred = (L < (int)n) && (vv <= mv + MARGIN2);
        u64 mask = __ballot(pred);
        int tot = __popcll(mask);
        if (tot > 0) {
            int leader = __ffsll((long long)mask) - 1;
            u32 base = 0;
            if (L == leader) base = atomicAdd(svcount, (u32)tot);
            base = __shfl(base, leader);
            if (pred) {
                u32 off = __popcll(mask & ((1ull << L) - 1));
                u32 pos = base + off;
                if (pos < SVCAP) survivors[pos] = make_uint2((u32)row, kk);
            }
        }
    } else {
        // overflow fallback: full exact scan (rare)
        float Ar = A[row];
        const float* xr = x + (size_t)row * DDIM;
        u64 best = 0xFFFFFFFFFFFFFFFFull;
        for (int c = 0; c < 64; ++c) {
            u32 k = c * 64 + L;
            float r = exact_r(xr, Ar, emb + (size_t)k * DDIM);
            u64 cand = ((u64)fkey(r) << 32) | (u64)k;
            best = (cand < best) ? cand : best;
        }
        #pragma unroll
        for (int o = 32; o; o >>= 1) {
            u64 other = __shfl_xor(best, o, 64);
            best = (other < best) ? other : best;
        }
        if (L == 0) atomicMin(&rmin[row], best);
    }
}

// ---------------------------------------------------------------- phase 2b
// one survivor per thread: exact fp32 distance, packed (key,k) atomicMin
__launch_bounds__(256)
__global__ void phase2b(const float* __restrict__ x, const float* __restrict__ emb,
                        const float* __restrict__ A, u64* __restrict__ rmin,
                        const u32* __restrict__ svcount, const uint2* __restrict__ survivors) {
    u32 total = *svcount;
    if (total > SVCAP) total = SVCAP;
    u32 stride = gridDim.x * blockDim.x;
    for (u32 i = blockIdx.x * blockDim.x + threadIdx.x; i < total; i += stride) {
        uint2 s = survivors[i];
        float r = exact_r(x + (size_t)s.x * DDIM, A[s.x], emb + (size_t)s.y * DDIM);
        atomicMin(&rmin[s.x], ((u64)fkey(r) << 32) | (u64)s.y);
    }
}

// ---------------------------------------------------------------- phase 2c
__launch_bounds__(256)
__global__ void phase2c(const float* __restrict__ emb, const u64* __restrict__ rmin,
                        float* __restrict__ outq, float* __restrict__ outp) {
    int row = blockIdx.x * 4 + (threadIdx.x >> 6);
    int L = threadIdx.x & 63;
    u32 kstar = (u32)(rmin[row] & 0xFFFFFFFFull);
    float4 q = ((const float4*)(emb + (size_t)kstar * DDIM))[L];
    ((float4*)(outq + (size_t)row * DDIM))[L] = q;
    if (L == 0) outp[row] = (float)kstar;
}

// ---------------------------------------------------------------- launch
extern "C" void kernel_launch(void* const* d_in, const int* in_sizes, int n_in,
                              void* d_out, int out_size, void* d_ws, size_t ws_size,
                              hipStream_t stream) {
    const float* x   = (const float*)d_in[0];   // [65536, 256] fp32
    const float* emb = (const float*)d_in[1];   // [4096, 256] fp32
    float* outq = (float*)d_out;                      // [65536,256]
    float* outp = outq + (size_t)NROWS * DDIM;        // [65536]

    char* ws = (char*)d_ws;
    u32*   ebf       = (u32*)ws;                                   // 2 MB
    u32*   cnt       = (u32*)(ws + (2u << 20));                    // 256 KB
    float* A         = (float*)(ws + (2u << 20) + (256u << 10));   // 256 KB
    u64*   rmin      = (u64*)(ws + (2u << 20) + (512u << 10));     // 512 KB
    u32*   svcount   = (u32*)(ws + (3u << 20));                    // 4 B
    uint2* survivors = (uint2*)(ws + (4u << 20));                  // 8 MB
    uint2* list      = (uint2*)(ws + (12u << 20));                 // 24 MB  (total 36 MB)

    hipMemsetAsync(cnt, 0, (size_t)NROWS * sizeof(u32), stream);
    hipMemsetAsync(rmin, 0xFF, (size_t)NROWS * sizeof(u64), stream);
    hipMemsetAsync(svcount, 0, sizeof(u32), stream);

    convert_e<<<1024, 256, 0, stream>>>(emb, ebf);
    computeA<<<NROWS / 4, 256, 0, stream>>>(x, A);
    phase1<<<NROWS / 128, 512, 0, stream>>>(x, ebf, cnt, list);
    phase2a<<<NROWS / 4, 256, 0, stream>>>(x, emb, A, cnt, list, rmin, svcount, survivors);
    phase2b<<<1024, 256, 0, stream>>>(x, emb, A, rmin, svcount, survivors);
    phase2c<<<NROWS / 4, 256, 0, stream>>>(emb, rmin, outq, outp);
}

// Round 3
// 742.284 us; speedup vs baseline: 1.9271x; 1.9271x over previous
//
#include <hip/hip_runtime.h>
#include <hip/hip_bf16.h>
#include <stdint.h>

#define NROWS 65536   // B*S = 16*4096
#define DDIM  256
#define KCAND 4096
#define CAP   48      // per-row candidate list slots
#define MARGIN1 8e-4f // phase-1 collect margin (worst-case bf16 err 2*2.8e-4 + tie grid)
#define MARGIN2 8e-4f // phase-2 prune margin

typedef __bf16 bf16x8 __attribute__((ext_vector_type(8)));
typedef float  f32x4  __attribute__((ext_vector_type(4)));
typedef unsigned int u32;
typedef unsigned long long u64;

__device__ __forceinline__ u32 f2bf_u(float f) {
    u32 u = __float_as_uint(f);
    u += 0x7fffu + ((u >> 16) & 1u);
    return u >> 16;
}
__device__ __forceinline__ u32 pack2(float lo, float hi) { return f2bf_u(lo) | (f2bf_u(hi) << 16); }
__device__ __forceinline__ u32 fkey(float f) {
    u32 u = __float_as_uint(f);
    return (u & 0x80000000u) ? ~u : (u | 0x80000000u);
}
__device__ __forceinline__ float funkey(u32 k) {
    u32 u = (k & 0x80000000u) ? (k ^ 0x80000000u) : ~k;
    return __uint_as_float(u);
}

// np-semantics exact distance: r = fl(fl(A + b_k) - acc_k), sequential ascending-d FMA
__device__ __forceinline__ float exact_r(const float* __restrict__ xr, float A,
                                         const float* __restrict__ er) {
    float b = 0.f, acc = 0.f;
    #pragma unroll 8
    for (int d = 0; d < DDIM; ++d) {
        float e = er[d];
        b   = fmaf(e, e, b);
        acc = fmaf(2.0f * xr[d], e, acc);
    }
    return (A + b) - acc;
}

// ---------------------------------------------------------------- convert
__global__ void convert_e(const float* __restrict__ e, u32* __restrict__ ebf) {
    int i = blockIdx.x * blockDim.x + threadIdx.x;  // 262144 float4 chunks
    float4 v = ((const float4*)e)[i];
    uint2 o; o.x = pack2(v.x, v.y); o.y = pack2(v.z, v.w);
    ((uint2*)ebf)[i] = o;
}

// ---------------------------------------------------------------- phase 1
// 512 thr = 8 waves (2 row x 4 col), wave-tile 64x64. x-tile resident (64KB,
// XOR-swizzled), e streamed in 64 dbuf'd 32KB chunks (BK=64), 1 barrier/chunk.
__launch_bounds__(512, 2)
__global__ void phase1(const float* __restrict__ x, const u32* __restrict__ ebf,
                       u32* __restrict__ cnt, uint2* __restrict__ list) {
    __shared__ u32 lxd[128 * 128];        // 128 rows x 128 dwords (256 bf16), swizzled
    __shared__ u32 led[2][256 * 32];      // 2 x (256 cands x 32 dwords = 64 bf16)
    __shared__ u32 rowMinU[128];

    const int tid = threadIdx.x;
    const int rowBase = blockIdx.x * 128;
    if (tid < 128) rowMinU[tid] = 0xFFFFFFFFu;

    // stage x tile once: fp32 -> bf16, swizzled
    {
        const float4* x4 = (const float4*)(x + (size_t)rowBase * DDIM);
        #pragma unroll
        for (int j = 0; j < 16; ++j) {
            int idx = j * 512 + tid;          // 0..8191 float4 chunks
            int r = idx >> 6, c4 = idx & 63;
            float4 v = x4[idx];
            int dst = r * 128 + ((2 * c4) ^ ((r & 7) << 2));
            lxd[dst]     = pack2(v.x, v.y);
            lxd[dst + 1] = pack2(v.z, v.w);
        }
    }

    const int L = tid & 63, w = tid >> 6;
    const int wr = w >> 2, wc = w & 3;
    const int lq = L >> 4, ln = L & 15;
    const int swz = (ln & 7) << 2;

    uint4 pf[4];
    auto loadStage = [&](int s) {
        int ct = s >> 2, kc = s & 3;
        #pragma unroll
        for (int i = 0; i < 4; ++i) {
            int idx = i * 512 + tid;          // 0..2047 uint4 chunks
            int q = idx >> 3, c16 = idx & 7;
            pf[i] = *(const uint4*)&ebf[(ct * 256 + q) * 128 + kc * 32 + c16 * 4];
        }
    };
    auto storeStage = [&](int s) {
        int buf = s & 1;
        #pragma unroll
        for (int i = 0; i < 4; ++i) {
            int idx = i * 512 + tid;
            int q = idx >> 3, c16 = idx & 7;
            int dst = q * 32 + ((c16 * 4) ^ ((q & 7) << 2));
            *(uint4*)&led[buf][dst] = pf[i];
        }
    };

    loadStage(0); storeStage(0);
    f32x4 acc[4][4];

    for (int s = 0; s < 64; ++s) {
        __syncthreads();                      // the ONLY barrier per chunk
        const int ct = s >> 2, kc = s & 3, buf = s & 1;
        if (s < 63) loadStage(s + 1);
        if (kc == 0) {
            #pragma unroll
            for (int a = 0; a < 4; ++a)
                #pragma unroll
                for (int u = 0; u < 4; ++u)
                    acc[a][u] = (f32x4){0.f, 0.f, 0.f, 0.f};
        }
        #pragma unroll
        for (int ksub = 0; ksub < 2; ++ksub) {
            bf16x8 fa[4], fb[4];
            #pragma unroll
            for (int t = 0; t < 4; ++t) {
                int R = wr * 64 + t * 16 + ln;
                int c = kc * 32 + ksub * 16 + lq * 4;
                fa[t] = *(const bf16x8*)&lxd[R * 128 + (c ^ swz)];
            }
            #pragma unroll
            for (int u = 0; u < 4; ++u) {
                int q = wc * 64 + u * 16 + ln;
                int c = ksub * 16 + lq * 4;
                fb[u] = *(const bf16x8*)&led[buf][q * 32 + (c ^ swz)];
            }
            #pragma unroll
            for (int a = 0; a < 4; ++a)
                #pragma unroll
                for (int u = 0; u < 4; ++u)
                    acc[a][u] = __builtin_amdgcn_mfma_f32_16x16x32_bf16(fa[a], fb[u], acc[a][u], 0, 0, 0);
        }
        if (kc == 3) {
            // epilogue: barrier-free (rowMinU monotone; stale threshold => superset)
            #pragma unroll
            for (int a = 0; a < 4; ++a) {
                #pragma unroll
                for (int r = 0; r < 4; ++r) {
                    float v0 = -2.f * acc[a][0][r], v1 = -2.f * acc[a][1][r];
                    float v2 = -2.f * acc[a][2][r], v3 = -2.f * acc[a][3][r];
                    float m = fminf(fminf(v0, v1), fminf(v2, v3));
                    int lrow = wr * 64 + a * 16 + lq * 4 + r;
                    u32 mk = fkey(m);
                    u32 old = atomicMin(&rowMinU[lrow], mk);
                    float thr = funkey(old < mk ? old : mk) + MARGIN1;
                    int grow = rowBase + lrow;
                    int kb = ct * 256 + wc * 64 + ln;
                    if (v0 <= thr) { u32 id = atomicAdd(&cnt[grow], 1u); if (id < CAP) list[(size_t)grow * CAP + id] = make_uint2(__float_as_uint(v0), kb); }
                    if (v1 <= thr) { u32 id = atomicAdd(&cnt[grow], 1u); if (id < CAP) list[(size_t)grow * CAP + id] = make_uint2(__float_as_uint(v1), kb + 16); }
                    if (v2 <= thr) { u32 id = atomicAdd(&cnt[grow], 1u); if (id < CAP) list[(size_t)grow * CAP + id] = make_uint2(__float_as_uint(v2), kb + 32); }
                    if (v3 <= thr) { u32 id = atomicAdd(&cnt[grow], 1u); if (id < CAP) list[(size_t)grow * CAP + id] = make_uint2(__float_as_uint(v3), kb + 48); }
                }
            }
        }
        if (s < 63) storeStage(s + 1);
    }
}

// ---------------------------------------------------------------- phase 2 (fused)
// One wave per row, 4 waves/block. No global atomics anywhere:
//   load x row -> LDS, A = sum(x^2) (fp64 reduce, inline);
//   prune collected candidates to within MARGIN2 of their min (~2 survive);
//   exact fp32 rescue per surviving lane (np-bit-exact sequential FMA chain);
//   packed (key,k) shuffle-min with lowest-index tie-break; gather + write.
__launch_bounds__(256)
__global__ void phase2(const float* __restrict__ x, const float* __restrict__ emb,
                       const u32* __restrict__ cnt, const uint2* __restrict__ list,
                       float* __restrict__ outq, float* __restrict__ outp) {
    __shared__ float xs[4][DDIM];
    const int wid = threadIdx.x >> 6;
    const int row = blockIdx.x * 4 + wid;
    const int L   = threadIdx.x & 63;

    float4 v = ((const float4*)(x + (size_t)row * DDIM))[L];
    *(float4*)&xs[wid][L * 4] = v;
    double s = (double)v.x * v.x + (double)v.y * v.y + (double)v.z * v.z + (double)v.w * v.w;
    #pragma unroll
    for (int o = 32; o; o >>= 1) s += __shfl_xor(s, o, 64);
    float A = (float)s;
    // per-wave LDS write->read: compiler inserts lgkmcnt wait; no barrier needed

    u32 n = cnt[row];
    u64 key = 0xFFFFFFFFFFFFFFFFull;

    if (n <= CAP) {
        float vv = INFINITY; u32 kk = 0;
        if (L < (int)n) { uint2 e = list[(size_t)row * CAP + L]; vv = __uint_as_float(e.x); kk = e.y; }
        float mv = vv;
        #pragma unroll
        for (int o = 32; o; o >>= 1) mv = fminf(mv, __shfl_xor(mv, o, 64));
        if (L < (int)n && vv <= mv + MARGIN2) {
            float r = exact_r(xs[wid], A, emb + (size_t)kk * DDIM);
            key = ((u64)fkey(r) << 32) | (u64)kk;
        }
    } else {
        // overflow fallback: full exact scan (rare)
        for (int c = 0; c < KCAND / 64; ++c) {
            u32 k = (u32)(c * 64 + L);
            float r = exact_r(xs[wid], A, emb + (size_t)k * DDIM);
            u64 cand = ((u64)fkey(r) << 32) | (u64)k;
            key = (cand < key) ? cand : key;
        }
    }
    #pragma unroll
    for (int o = 32; o; o >>= 1) {
        u64 other = __shfl_xor(key, o, 64);
        key = (other < key) ? other : key;
    }
    u32 kstar = (u32)(key & 0xFFFFFFFFull);

    float4 q = ((const float4*)(emb + (size_t)kstar * DDIM))[L];
    ((float4*)(outq + (size_t)row * DDIM))[L] = q;
    if (L == 0) outp[row] = (float)kstar;
}

// ---------------------------------------------------------------- launch
extern "C" void kernel_launch(void* const* d_in, const int* in_sizes, int n_in,
                              void* d_out, int out_size, void* d_ws, size_t ws_size,
                              hipStream_t stream) {
    const float* x   = (const float*)d_in[0];   // [65536, 256] fp32
    const float* emb = (const float*)d_in[1];   // [4096, 256] fp32
    float* outq = (float*)d_out;                      // [65536,256]
    float* outp = outq + (size_t)NROWS * DDIM;        // [65536]

    char* ws = (char*)d_ws;
    u32*   ebf  = (u32*)ws;                           // 2 MB
    u32*   cnt  = (u32*)(ws + (2u << 20));            // 256 KB
    uint2* list = (uint2*)(ws + (3u << 20));          // 24 MB (total 27 MB)

    hipMemsetAsync(cnt, 0, (size_t)NROWS * sizeof(u32), stream);
    convert_e<<<1024, 256, 0, stream>>>(emb, ebf);
    phase1<<<NROWS / 128, 512, 0, stream>>>(x, ebf, cnt, list);
    phase2<<<NROWS / 4, 256, 0, stream>>>(x, emb, cnt, list, outq, outp);
}

// Round 4
// 660.338 us; speedup vs baseline: 2.1663x; 1.1241x over previous
//
#include <hip/hip_runtime.h>
#include <hip/hip_bf16.h>
#include <stdint.h>

#define NROWS 65536   // B*S = 16*4096
#define DDIM  256
#define KCAND 4096
#define CAP   48      // per-row candidate list slots
#define MARGIN1 8e-4f // phase-1 collect margin (worst-case bf16 err 2*2.2e-4 + tie grid)
#define MARGIN2 8e-4f // phase-2 prune margin

typedef __bf16 bf16x8 __attribute__((ext_vector_type(8)));
typedef float  f32x4  __attribute__((ext_vector_type(4)));
typedef unsigned int u32;
typedef unsigned long long u64;

__device__ __forceinline__ u32 f2bf_u(float f) {
    u32 u = __float_as_uint(f);
    u += 0x7fffu + ((u >> 16) & 1u);
    return u >> 16;
}
__device__ __forceinline__ u32 pack2(float lo, float hi) { return f2bf_u(lo) | (f2bf_u(hi) << 16); }
__device__ __forceinline__ u32 fkey(float f) {
    u32 u = __float_as_uint(f);
    return (u & 0x80000000u) ? ~u : (u | 0x80000000u);
}
__device__ __forceinline__ float funkey(u32 k) {
    u32 u = (k & 0x80000000u) ? (k ^ 0x80000000u) : ~k;
    return __uint_as_float(u);
}
__device__ __forceinline__ void gld_lds16(const u32* g, u32* l) {
    __builtin_amdgcn_global_load_lds((const __attribute__((address_space(1))) u32*)g,
                                     (__attribute__((address_space(3))) u32*)l, 16, 0, 0);
}

// np-semantics exact distance: r = fl(fl(A + b_k) - acc_k), sequential ascending-d FMA
__device__ __forceinline__ float exact_r(const float* __restrict__ xr, float A,
                                         const float* __restrict__ er) {
    float b = 0.f, acc = 0.f;
    #pragma unroll 8
    for (int d = 0; d < DDIM; ++d) {
        float e = er[d];
        b   = fmaf(e, e, b);
        acc = fmaf(2.0f * xr[d], e, acc);
    }
    return (A + b) - acc;
}

// ---------------------------------------------------------------- convert
// ebf layout: cand-major, 128 dwords (256 bf16) per cand, quad-swizzled so
// that phase1's lane-linear global_load_lds DMA lands bank-conflict-free:
// within each 16-dword kc-slice, logical quad lq is stored at lq ^ ((q>>1)&3).
__launch_bounds__(256)
__global__ void convert_e(const float* __restrict__ e, u32* __restrict__ ebf) {
    int T = blockIdx.x * blockDim.x + threadIdx.x;   // 131072 dest uint4 quads
    int q = T >> 5, t = T & 31;                      // cand, quad-in-row
    int kc = t >> 2, j = t & 3;
    int sw = (q >> 1) & 3;
    int ds = kc * 16 + ((j ^ sw) << 2);              // source logical dword base
    const float4* src = (const float4*)(e + (size_t)q * DDIM + ds * 2);
    float4 a = src[0], b = src[1];
    uint4 o;
    o.x = pack2(a.x, a.y); o.y = pack2(a.z, a.w);
    o.z = pack2(b.x, b.y); o.w = pack2(b.z, b.w);
    ((uint4*)ebf)[T] = o;
}

// ---------------------------------------------------------------- phase 1
// 256 thr = 4 waves, block tile 64 rows x 4096 cands. LDS 64.3KB -> 2 blk/CU.
// x resident bf16 (swizzled); e DMA'd via global_load_lds in 128 dbuf'd 16KB
// chunks (256 cands x 32 D). Wave w owns cand strip w*64..+64 (4x4 16x16x32).
// Epilogue per cand-tile: group-reduced LDS atomicMin + ballot-skipped,
// prefix-aggregated collection (1 global atomic per 16-lane group max).
__launch_bounds__(256, 2)
__global__ void phase1(const float* __restrict__ x, const u32* __restrict__ ebf,
                       u32* __restrict__ cnt, uint2* __restrict__ list) {
    __shared__ u32 lxd[64 * 128];        // 64 rows x 128 dwords, XOR-swizzled
    __shared__ u32 led[2][256 * 16];     // 2 x (256 cands x 16 dwords = 32 D)
    __shared__ u32 rowMinU[64];

    const int tid = threadIdx.x;
    const int rowBase = blockIdx.x * 64;
    if (tid < 64) rowMinU[tid] = 0xFFFFFFFFu;

    // stage x tile once: fp32 -> bf16, swizzled (logical dword d at d^((r&7)<<2))
    {
        const float4* x4 = (const float4*)(x + (size_t)rowBase * DDIM);
        #pragma unroll
        for (int j = 0; j < 16; ++j) {
            int idx = j * 256 + tid;          // 0..4095 float4 chunks
            int r = idx >> 6, c4 = idx & 63;
            float4 v = x4[idx];
            int dst = r * 128 + ((2 * c4) ^ ((r & 7) << 2));
            *(uint2*)&lxd[dst] = make_uint2(pack2(v.x, v.y), pack2(v.z, v.w));
        }
    }

    const int L = tid & 63, w = tid >> 6;     // w = cand-strip (wc)
    const int lq = L >> 4, ln = L & 15;
    const int swz = (ln & 7) << 2;
    const int bquad = (lq ^ ((ln >> 1) & 3)) << 2;   // un-swizzle for fb reads
    const int laneoff = (L >> 2) * 128 + (L & 3) * 4; // DMA per-lane ebf dword offset

    auto dma = [&](int s) {
        int ct = s >> 3, kc = s & 7;
        u32* lb = &led[s & 1][0];
        const u32* gb = ebf + (size_t)(ct * 256) * 128 + kc * 16 + laneoff;
        #pragma unroll
        for (int i = 0; i < 4; ++i) {
            int seg = w * 4 + i;              // 16 cands per 1KB wave-load
            gld_lds16(gb + seg * 16 * 128, lb + seg * 256);
        }
    };

    f32x4 acc[4][4];
    dma(0);

    for (int s = 0; s < 128; ++s) {
        __syncthreads();                      // single barrier per chunk
        const int kc = s & 7, buf = s & 1;
        if (s < 127) dma(s + 1);
        if (kc == 0) {
            #pragma unroll
            for (int a = 0; a < 4; ++a)
                #pragma unroll
                for (int u = 0; u < 4; ++u)
                    acc[a][u] = (f32x4){0.f, 0.f, 0.f, 0.f};
        }
        bf16x8 fa[4], fb[4];
        #pragma unroll
        for (int t = 0; t < 4; ++t)
            fa[t] = *(const bf16x8*)&lxd[(t * 16 + ln) * 128 + ((kc * 16 + lq * 4) ^ swz)];
        #pragma unroll
        for (int u = 0; u < 4; ++u) {
            int q = w * 64 + u * 16 + ln;
            fb[u] = *(const bf16x8*)&led[buf][q * 16 + bquad];
        }
        #pragma unroll
        for (int a = 0; a < 4; ++a)
            #pragma unroll
            for (int u = 0; u < 4; ++u)
                acc[a][u] = __builtin_amdgcn_mfma_f32_16x16x32_bf16(fa[a], fb[u], acc[a][u], 0, 0, 0);

        if (kc == 7) {
            int ct = s >> 3;
            #pragma unroll
            for (int a = 0; a < 4; ++a) {
                #pragma unroll
                for (int r = 0; r < 4; ++r) {
                    float v0 = -2.f * acc[a][0][r], v1 = -2.f * acc[a][1][r];
                    float v2 = -2.f * acc[a][2][r], v3 = -2.f * acc[a][3][r];
                    float m = fminf(fminf(v0, v1), fminf(v2, v3));
                    #pragma unroll
                    for (int o = 1; o <= 8; o <<= 1) m = fminf(m, __shfl_xor(m, o, 64));
                    int lrow = a * 16 + lq * 4 + r;
                    u32 mk = fkey(m);
                    if (ln == 0) atomicMin(&rowMinU[lrow], mk);
                    u32 seen = rowMinU[lrow];     // stale-high OK: superset-safe
                    float thr = funkey(seen < mk ? seen : mk) + MARGIN1;
                    int c0 = (v0 <= thr) + (v1 <= thr) + (v2 <= thr) + (v3 <= thr);
                    if (__ballot(c0 != 0)) {      // skip whole block when nothing fires
                        int sum = c0;
                        #pragma unroll
                        for (int o = 1; o < 16; o <<= 1) {
                            int t = __shfl_up(sum, o, 64);
                            if (ln >= o) sum += t;
                        }
                        int pre = sum - c0;
                        int grow = rowBase + lrow;
                        u32 base = 0;
                        if (ln == 15 && sum > 0) base = atomicAdd(&cnt[grow], (u32)sum);
                        base = __shfl(base, (L & ~15) | 15, 64);
                        u32 pos = base + (u32)pre;
                        int kb = ct * 256 + w * 64 + ln;
                        if (v0 <= thr) { if (pos < CAP) list[(size_t)grow * CAP + pos] = make_uint2(__float_as_uint(v0), kb);      ++pos; }
                        if (v1 <= thr) { if (pos < CAP) list[(size_t)grow * CAP + pos] = make_uint2(__float_as_uint(v1), kb + 16); ++pos; }
                        if (v2 <= thr) { if (pos < CAP) list[(size_t)grow * CAP + pos] = make_uint2(__float_as_uint(v2), kb + 32); ++pos; }
                        if (v3 <= thr) { if (pos < CAP) list[(size_t)grow * CAP + pos] = make_uint2(__float_as_uint(v3), kb + 48); }
                    }
                }
            }
        }
    }
}

// ---------------------------------------------------------------- phase 2 (fused)
// One wave per row, 4 waves/block; prune -> exact fp32 rescue (np-bit-exact) ->
// packed shuffle-min tie-break -> gather + write. No global atomics.
__launch_bounds__(256)
__global__ void phase2(const float* __restrict__ x, const float* __restrict__ emb,
                       const u32* __restrict__ cnt, const uint2* __restrict__ list,
                       float* __restrict__ outq, float* __restrict__ outp) {
    __shared__ float xs[4][DDIM];
    const int wid = threadIdx.x >> 6;
    const int row = blockIdx.x * 4 + wid;
    const int L   = threadIdx.x & 63;

    float4 v = ((const float4*)(x + (size_t)row * DDIM))[L];
    *(float4*)&xs[wid][L * 4] = v;
    double s = (double)v.x * v.x + (double)v.y * v.y + (double)v.z * v.z + (double)v.w * v.w;
    #pragma unroll
    for (int o = 32; o; o >>= 1) s += __shfl_xor(s, o, 64);
    float A = (float)s;

    u32 n = cnt[row];
    u64 key = 0xFFFFFFFFFFFFFFFFull;

    if (n <= CAP) {
        float vv = INFINITY; u32 kk = 0;
        if (L < (int)n) { uint2 e = list[(size_t)row * CAP + L]; vv = __uint_as_float(e.x); kk = e.y; }
        float mv = vv;
        #pragma unroll
        for (int o = 32; o; o >>= 1) mv = fminf(mv, __shfl_xor(mv, o, 64));
        if (L < (int)n && vv <= mv + MARGIN2) {
            float r = exact_r(xs[wid], A, emb + (size_t)kk * DDIM);
            key = ((u64)fkey(r) << 32) | (u64)kk;
        }
    } else {
        for (int c = 0; c < KCAND / 64; ++c) {
            u32 k = (u32)(c * 64 + L);
            float r = exact_r(xs[wid], A, emb + (size_t)k * DDIM);
            u64 cand = ((u64)fkey(r) << 32) | (u64)k;
            key = (cand < key) ? cand : key;
        }
    }
    #pragma unroll
    for (int o = 32; o; o >>= 1) {
        u64 other = __shfl_xor(key, o, 64);
        key = (other < key) ? other : key;
    }
    u32 kstar = (u32)(key & 0xFFFFFFFFull);

    float4 q = ((const float4*)(emb + (size_t)kstar * DDIM))[L];
    ((float4*)(outq + (size_t)row * DDIM))[L] = q;
    if (L == 0) outp[row] = (float)kstar;
}

// ---------------------------------------------------------------- launch
extern "C" void kernel_launch(void* const* d_in, const int* in_sizes, int n_in,
                              void* d_out, int out_size, void* d_ws, size_t ws_size,
                              hipStream_t stream) {
    const float* x   = (const float*)d_in[0];   // [65536, 256] fp32
    const float* emb = (const float*)d_in[1];   // [4096, 256] fp32
    float* outq = (float*)d_out;                      // [65536,256]
    float* outp = outq + (size_t)NROWS * DDIM;        // [65536]

    char* ws = (char*)d_ws;
    u32*   ebf  = (u32*)ws;                           // 2 MB (swizzled bf16)
    u32*   cnt  = (u32*)(ws + (2u << 20));            // 256 KB
    uint2* list = (uint2*)(ws + (3u << 20));          // 24 MB (total 27 MB)

    hipMemsetAsync(cnt, 0, (size_t)NROWS * sizeof(u32), stream);
    convert_e<<<512, 256, 0, stream>>>(emb, ebf);
    phase1<<<NROWS / 64, 256, 0, stream>>>(x, ebf, cnt, list);
    phase2<<<NROWS / 4, 256, 0, stream>>>(x, emb, cnt, list, outq, outp);
}

// Round 5
// 619.378 us; speedup vs baseline: 2.3095x; 1.0661x over previous
//
#include <hip/hip_runtime.h>
#include <hip/hip_bf16.h>
#include <stdint.h>

#define NROWS 65536   // B*S = 16*4096
#define DDIM  256
#define KCAND 4096
#define CAP   48      // per-row candidate list slots
#define MARGIN1 8e-4f // phase-1 collect margin (worst-case bf16 err 2*2.2e-4 + tie grid)
#define MARGIN2 8e-4f // phase-2 prune margin

typedef __bf16 bf16x8 __attribute__((ext_vector_type(8)));
typedef float  f32x4  __attribute__((ext_vector_type(4)));
typedef unsigned int u32;
typedef unsigned long long u64;

__device__ __forceinline__ u32 f2bf_u(float f) {
    u32 u = __float_as_uint(f);
    u += 0x7fffu + ((u >> 16) & 1u);
    return u >> 16;
}
__device__ __forceinline__ u32 pack2(float lo, float hi) { return f2bf_u(lo) | (f2bf_u(hi) << 16); }
__device__ __forceinline__ u32 fkey(float f) {
    u32 u = __float_as_uint(f);
    return (u & 0x80000000u) ? ~u : (u | 0x80000000u);
}
__device__ __forceinline__ float funkey(u32 k) {
    u32 u = (k & 0x80000000u) ? (k ^ 0x80000000u) : ~k;
    return __uint_as_float(u);
}

// np-semantics exact distance: r = fl(fl(A + b_k) - acc_k), sequential ascending-d FMA
__device__ __forceinline__ float exact_r(const float* __restrict__ xr, float A,
                                         const float* __restrict__ er) {
    float b = 0.f, acc = 0.f;
    #pragma unroll 8
    for (int d = 0; d < DDIM; ++d) {
        float e = er[d];
        b   = fmaf(e, e, b);
        acc = fmaf(2.0f * xr[d], e, acc);
    }
    return (A + b) - acc;
}

// ---------------------------------------------------------------- convert
// ebf frag-major: tile (c16, kb) = 64 lanes x 16B, lane L holds
// B[n = c16*16 + (L&15)][k = kb*32 + (L>>4)*8 .. +8] as 8 bf16.
// A wave's B-frag load = one coalesced global_load_dwordx4 (1KB).
__launch_bounds__(256)
__global__ void convert_e(const float* __restrict__ e, u32* __restrict__ ebf) {
    int T = blockIdx.x * blockDim.x + threadIdx.x;   // 131072 = 256 c16 * 8 kb * 64 lanes
    int L = T & 63, kb = (T >> 6) & 7, c16 = T >> 9;
    int cand = c16 * 16 + (L & 15);
    int k0 = kb * 32 + (L >> 4) * 8;
    const float4* src = (const float4*)(e + (size_t)cand * DDIM + k0);
    float4 a = src[0], b = src[1];
    uint4 o;
    o.x = pack2(a.x, a.y); o.y = pack2(a.z, a.w);
    o.z = pack2(b.x, b.y); o.w = pack2(b.z, b.w);
    ((uint4*)ebf)[T] = o;
}

// ---------------------------------------------------------------- phase 1
// 256 thr = 4 waves, tile 64 rows x 4096 cands. x resident bf16 in LDS
// (32.3KB, ONE barrier total); e loaded per-wave straight to VGPRs from the
// frag-major ebf (L2-resident), double-buffered — barrier-free K-loop.
// Wave w owns cand strip it*4+w per iteration (64 cands, 4x4 16x16x32 MFMAs).
// Epilogue per strip: 16-lane-group shuffle-min -> 1 LDS atomicMin, ballot-
// skipped prefix-aggregated collection -> <=1 global atomic per group.
__launch_bounds__(256, 3)
__global__ void phase1(const float* __restrict__ x, const u32* __restrict__ ebf,
                       u32* __restrict__ cnt, uint2* __restrict__ list) {
    __shared__ u32 lxd[64 * 128];        // 64 rows x 128 dwords, XOR-swizzled
    __shared__ u32 rowMinU[64];

    const int tid = threadIdx.x;
    const int rowBase = blockIdx.x * 64;
    if (tid < 64) rowMinU[tid] = 0xFFFFFFFFu;

    // stage x tile once: fp32 -> bf16, swizzled (logical dword d at d^((r&7)<<2))
    {
        const float4* x4 = (const float4*)(x + (size_t)rowBase * DDIM);
        #pragma unroll
        for (int j = 0; j < 16; ++j) {
            int idx = j * 256 + tid;          // 0..4095 float4 chunks
            int r = idx >> 6, c4 = idx & 63;
            float4 v = x4[idx];
            int dst = r * 128 + ((2 * c4) ^ ((r & 7) << 2));
            *(uint2*)&lxd[dst] = make_uint2(pack2(v.x, v.y), pack2(v.z, v.w));
        }
    }
    __syncthreads();                          // the ONLY barrier in the kernel

    const int L = tid & 63, w = tid >> 6;
    const int lq = L >> 4, ln = L & 15;
    const int swz = (ln & 7) << 2;
    const u32* ebL = ebf + L * 4;

    auto loadB = [&](int g, bf16x8* dst) {    // g = it*8 + kc
        int it = g >> 3, kc = g & 7;
        int strip = it * 4 + w;
        const u32* gb = ebL + ((size_t)(strip * 4) * 8 + kc) * 256;
        #pragma unroll
        for (int u = 0; u < 4; ++u)
            dst[u] = *(const bf16x8*)(gb + u * 8 * 256);  // c16 stride = 2048 dwords
    };

    bf16x8 bb[2][4];
    loadB(0, bb[0]);
    f32x4 acc[4][4];

    for (int it = 0; it < 16; ++it) {
        #pragma unroll
        for (int a = 0; a < 4; ++a)
            #pragma unroll
            for (int u = 0; u < 4; ++u)
                acc[a][u] = (f32x4){0.f, 0.f, 0.f, 0.f};

        #pragma unroll
        for (int kc = 0; kc < 8; ++kc) {
            int g = it * 8 + kc;
            if (g < 127) loadB(g + 1, bb[(kc + 1) & 1]);   // reg prefetch, no barrier
            bf16x8 fa[4];
            #pragma unroll
            for (int t = 0; t < 4; ++t)
                fa[t] = *(const bf16x8*)&lxd[(t * 16 + ln) * 128 + ((kc * 16 + lq * 4) ^ swz)];
            #pragma unroll
            for (int a = 0; a < 4; ++a)
                #pragma unroll
                for (int u = 0; u < 4; ++u)
                    acc[a][u] = __builtin_amdgcn_mfma_f32_16x16x32_bf16(fa[a], bb[kc & 1][u], acc[a][u], 0, 0, 0);
        }

        // epilogue for this strip (cands strip*64 .. +64)
        int strip = it * 4 + w;
        #pragma unroll
        for (int a = 0; a < 4; ++a) {
            #pragma unroll
            for (int r = 0; r < 4; ++r) {
                float v0 = -2.f * acc[a][0][r], v1 = -2.f * acc[a][1][r];
                float v2 = -2.f * acc[a][2][r], v3 = -2.f * acc[a][3][r];
                float m = fminf(fminf(v0, v1), fminf(v2, v3));
                #pragma unroll
                for (int o = 1; o <= 8; o <<= 1) m = fminf(m, __shfl_xor(m, o, 64));
                int lrow = a * 16 + lq * 4 + r;
                u32 mk = fkey(m);
                if (ln == 0) atomicMin(&rowMinU[lrow], mk);
                u32 seen = rowMinU[lrow];     // stale-high OK: superset-safe
                float thr = funkey(seen < mk ? seen : mk) + MARGIN1;
                int c0 = (v0 <= thr) + (v1 <= thr) + (v2 <= thr) + (v3 <= thr);
                if (__ballot(c0 != 0)) {      // skip whole group-block when nothing fires
                    int sum = c0;
                    #pragma unroll
                    for (int o = 1; o < 16; o <<= 1) {
                        int t = __shfl_up(sum, o, 64);
                        if (ln >= o) sum += t;
                    }
                    int pre = sum - c0;
                    int grow = rowBase + lrow;
                    u32 base = 0;
                    if (ln == 15 && sum > 0) base = atomicAdd(&cnt[grow], (u32)sum);
                    base = __shfl(base, (L & ~15) | 15, 64);
                    u32 pos = base + (u32)pre;
                    int kb = strip * 64 + ln;
                    if (v0 <= thr) { if (pos < CAP) list[(size_t)grow * CAP + pos] = make_uint2(__float_as_uint(v0), kb);      ++pos; }
                    if (v1 <= thr) { if (pos < CAP) list[(size_t)grow * CAP + pos] = make_uint2(__float_as_uint(v1), kb + 16); ++pos; }
                    if (v2 <= thr) { if (pos < CAP) list[(size_t)grow * CAP + pos] = make_uint2(__float_as_uint(v2), kb + 32); ++pos; }
                    if (v3 <= thr) { if (pos < CAP) list[(size_t)grow * CAP + pos] = make_uint2(__float_as_uint(v3), kb + 48); }
                }
            }
        }
    }
}

// ---------------------------------------------------------------- phase 2 (fused)
// One wave per row, 4 waves/block; n==1 fast path (sole margin-survivor wins
// by the collection invariant) else prune -> exact fp32 rescue (np-bit-exact)
// -> packed shuffle-min tie-break. Then gather + write. No global atomics.
__launch_bounds__(256)
__global__ void phase2(const float* __restrict__ x, const float* __restrict__ emb,
                       const u32* __restrict__ cnt, const uint2* __restrict__ list,
                       float* __restrict__ outq, float* __restrict__ outp) {
    __shared__ float xs[4][DDIM];
    const int wid = threadIdx.x >> 6;
    const int row = blockIdx.x * 4 + wid;
    const int L   = threadIdx.x & 63;

    u32 n = cnt[row];
    u32 kstar;

    if (n == 1) {
        kstar = list[(size_t)row * CAP].y;    // unique candidate: no rescue needed
    } else {
        float4 v = ((const float4*)(x + (size_t)row * DDIM))[L];
        *(float4*)&xs[wid][L * 4] = v;
        double s = (double)v.x * v.x + (double)v.y * v.y + (double)v.z * v.z + (double)v.w * v.w;
        #pragma unroll
        for (int o = 32; o; o >>= 1) s += __shfl_xor(s, o, 64);
        float A = (float)s;

        u64 key = 0xFFFFFFFFFFFFFFFFull;
        if (n <= CAP) {
            float vv = INFINITY; u32 kk = 0;
            if (L < (int)n) { uint2 e = list[(size_t)row * CAP + L]; vv = __uint_as_float(e.x); kk = e.y; }
            float mv = vv;
            #pragma unroll
            for (int o = 32; o; o >>= 1) mv = fminf(mv, __shfl_xor(mv, o, 64));
            if (L < (int)n && vv <= mv + MARGIN2) {
                float r = exact_r(xs[wid], A, emb + (size_t)kk * DDIM);
                key = ((u64)fkey(r) << 32) | (u64)kk;
            }
        } else {
            for (int c = 0; c < KCAND / 64; ++c) {
                u32 k = (u32)(c * 64 + L);
                float r = exact_r(xs[wid], A, emb + (size_t)k * DDIM);
                u64 cand = ((u64)fkey(r) << 32) | (u64)k;
                key = (cand < key) ? cand : key;
            }
        }
        #pragma unroll
        for (int o = 32; o; o >>= 1) {
            u64 other = __shfl_xor(key, o, 64);
            key = (other < key) ? other : key;
        }
        kstar = (u32)(key & 0xFFFFFFFFull);
    }

    float4 q = ((const float4*)(emb + (size_t)kstar * DDIM))[L];
    ((float4*)(outq + (size_t)row * DDIM))[L] = q;
    if (L == 0) outp[row] = (float)kstar;
}

// ---------------------------------------------------------------- launch
extern "C" void kernel_launch(void* const* d_in, const int* in_sizes, int n_in,
                              void* d_out, int out_size, void* d_ws, size_t ws_size,
                              hipStream_t stream) {
    const float* x   = (const float*)d_in[0];   // [65536, 256] fp32
    const float* emb = (const float*)d_in[1];   // [4096, 256] fp32
    float* outq = (float*)d_out;                      // [65536,256]
    float* outp = outq + (size_t)NROWS * DDIM;        // [65536]

    char* ws = (char*)d_ws;
    u32*   ebf  = (u32*)ws;                           // 2 MB (frag-major bf16)
    u32*   cnt  = (u32*)(ws + (2u << 20));            // 256 KB
    uint2* list = (uint2*)(ws + (3u << 20));          // 24 MB (total 27 MB)

    hipMemsetAsync(cnt, 0, (size_t)NROWS * sizeof(u32), stream);
    convert_e<<<512, 256, 0, stream>>>(emb, ebf);
    phase1<<<NROWS / 64, 256, 0, stream>>>(x, ebf, cnt, list);
    phase2<<<NROWS / 4, 256, 0, stream>>>(x, emb, cnt, list, outq, outp);
}